// Round 5
// baseline (6516.622 us; speedup 1.0000x reference)
//
#include <hip/hip_runtime.h>

#define B 256
#define T 2048
#define HDIM 128
#define CH 256
#define NCHUNK (T / CH)

typedef _Float16 f16;
typedef _Float16 h2 __attribute__((ext_vector_type(2)));
typedef _Float16 f16x8 __attribute__((ext_vector_type(8)));
typedef float f32x4 __attribute__((ext_vector_type(4)));

__device__ __forceinline__ float dot2(h2 a, h2 b, float c) {
#if __has_builtin(__builtin_amdgcn_fdot2)
    return __builtin_amdgcn_fdot2(a, b, c, false);
#else
    return c + (float)a[0] * (float)b[0] + (float)a[1] * (float)b[1];
#endif
}

__device__ __forceinline__ float sigm(float x) { return 1.0f / (1.0f + __expf(-x)); }
__device__ __forceinline__ float tanh_(float x) {
    float e = __expf(-2.0f * fabsf(x));
    float t = (1.0f - e) / (1.0f + e);
    return copysignf(t, x);
}

__device__ __forceinline__ void bar() {
    // LDS-only barrier: order ds ops but do NOT drain vmcnt (keeps prefetch
    // loads and y-stores in flight across the barrier).
    asm volatile("s_waitcnt lgkmcnt(0)" ::: "memory");
    __builtin_amdgcn_s_barrier();
}

// ---------------- fc1: scent[B,T,3] -> x1[T,B,32] f16 (24 real + 8 zero pad) ---------
__global__ __launch_bounds__(256) void fc1_kernel(
    const float* __restrict__ scent,
    const float* __restrict__ W1, const float* __restrict__ b1,
    const float* __restrict__ W2, const float* __restrict__ b2,
    f16* __restrict__ x1) {
    int r = blockIdx.x * 256 + threadIdx.x;   // r = b*T + t
    int b = r >> 11, t = r & 2047;
    float s0 = scent[r * 3], s1 = scent[r * 3 + 1], s2 = scent[r * 3 + 2];
    float a[12];
#pragma unroll
    for (int i = 0; i < 12; i++) {
        float v = W1[i * 3] * s0 + W1[i * 3 + 1] * s1 + W1[i * 3 + 2] * s2 + b1[i];
        a[i] = fmaxf(v, 0.f);
    }
    union { f16 o[32]; uint4 u[4]; } U;
#pragma unroll
    for (int j = 0; j < 24; j++) {
        float v = b2[j];
#pragma unroll
        for (int i = 0; i < 12; i++) v = fmaf(W2[j * 12 + i], a[i], v);
        U.o[j] = (f16)fmaxf(v, 0.f);
    }
#pragma unroll
    for (int j = 24; j < 32; j++) U.o[j] = (f16)0.f;
    uint4* d4 = (uint4*)(x1 + ((size_t)t * B + b) * 32);
#pragma unroll
    for (int i = 0; i < 4; i++) d4[i] = U.u[i];
}

// ---------------- pack Wf1 f32 -> half2 ----------------
__global__ __launch_bounds__(256) void pack_kernel(const float* __restrict__ w,
                                                   unsigned int* __restrict__ o) {
    int i = blockIdx.x * 256 + threadIdx.x;
    if (i < 4096) {
        union { h2 h; unsigned int u; } U;
        U.h[0] = (f16)w[2 * i];
        U.h[1] = (f16)w[2 * i + 1];
        o[i] = U.u;
    }
}

// ---------------- gx pre-GEMM: gx[r,g] = x[r,:]@Wih^T + bih + bhh (one chunk) --------
// Block: 64 rows x 128 gates; 4 waves, wave = 32 rows x 64 gates
// = 2 row-tiles x 4 gate-tiles (16x16) x KF kfrags of mfma_f32_16x16x32_f16.
template <int KIN, int KREAL, int SP>
__global__ __launch_bounds__(256) void gx_gemm(
    const f16* __restrict__ x,     // [T][B][KIN]
    const float* __restrict__ Wih, // [512][KREAL]
    const float* __restrict__ bih, const float* __restrict__ bhh,
    f16* __restrict__ gx,          // [CH*B][512]
    int t0) {
    constexpr int KF = KIN / 32;
    __shared__ __align__(16) f16 Alds[64 * SP];   // SP: padded row stride (bank spread)
    const int tid = threadIdx.x;
    const int mb = blockIdx.x, nb = blockIdx.y;
    const int l = tid & 63, wv = tid >> 6;
    const int lc = l & 15, lg = l >> 4;

    // ---- stage A slab: 64 consecutive (t,b) rows ----
    const f16* xrow = x + ((size_t)t0 * B + (size_t)mb * 64) * KIN;
    if (KIN == 128) {
#pragma unroll
        for (int it = 0; it < 4; it++) {
            int row = it * 16 + (tid >> 4), cc = tid & 15;
            uint4 v = *(const uint4*)(xrow + (size_t)row * KIN + cc * 8);
            *(uint4*)(&Alds[row * SP + cc * 8]) = v;
        }
    } else {
        int row = tid >> 2, cc = tid & 3;
        uint4 v = *(const uint4*)(xrow + (size_t)row * KIN + cc * 8);
        *(uint4*)(&Alds[row * SP + cc * 8]) = v;
    }

    // ---- B fragments (Wih f32 -> f16) + bias, registers ----
    const int gbase = nb * 128 + (wv & 1) * 64;
    const int rbase = (wv >> 1) * 32;
    f16x8 bf[4][KF];
    float bias4[4];
#pragma unroll
    for (int gt = 0; gt < 4; gt++) {
        int g = gbase + gt * 16 + lc;
        bias4[gt] = bih[g] + bhh[g];
#pragma unroll
        for (int kf = 0; kf < KF; kf++) {
            f16x8 v;
#pragma unroll
            for (int j = 0; j < 8; j++) {
                int k = kf * 32 + lg * 8 + j;
                v[j] = (k < KREAL) ? (f16)Wih[(size_t)g * KREAL + k] : (f16)0.f;
            }
            bf[gt][kf] = v;
        }
    }
    __syncthreads();

    f32x4 acc[2][4] = {};
#pragma unroll
    for (int kf = 0; kf < KF; kf++) {
#pragma unroll
        for (int rt = 0; rt < 2; rt++) {
            f16x8 af = *(const f16x8*)(&Alds[(rbase + rt * 16 + lc) * SP + kf * 32 + lg * 8]);
#pragma unroll
            for (int gt = 0; gt < 4; gt++)
                acc[rt][gt] = __builtin_amdgcn_mfma_f32_16x16x32_f16(af, bf[gt][kf], acc[rt][gt], 0, 0, 0);
        }
    }
    // ---- epilogue: C row = lg*4+q, col = lc (m89-verified layout) ----
#pragma unroll
    for (int rt = 0; rt < 2; rt++)
#pragma unroll
        for (int gt = 0; gt < 4; gt++)
#pragma unroll
            for (int q = 0; q < 4; q++) {
                int rr = mb * 64 + rbase + rt * 16 + lg * 4 + q;
                int gg = gbase + gt * 16 + lc;
                gx[(size_t)rr * 512 + gg] = (f16)(acc[rt][gt][q] + bias4[gt]);
            }
}

// ---------------- recurrence: one block (512 thr) per batch row, one chunk ----------
// thread = (grp=tid>>3 : 8 gates, s=tid&7 : 16-k slice of h). Whh f16 in VGPRs
// (64 dwords -- the ONLY weight array now => no AGPR shuffling). gx streamed
// with an 8-deep coalesced u16 prefetch ring. h,c state in hS/cS across chunks.
__global__ __attribute__((amdgpu_flat_work_group_size(512, 512), amdgpu_waves_per_eu(2, 2)))
void lstm_rec(
    const f16* __restrict__ gx,    // [CH*B][512]
    const float* __restrict__ Whh, // [512][128]
    f16* __restrict__ y,           // [T][B][128]
    float* __restrict__ hS, float* __restrict__ cS,  // [B][128] state (= hT/cT out)
    int t0, int init) {
    __shared__ __align__(16) f16 hbuf[HDIM];
    __shared__ float gbuf[512];
    const int tid = threadIdx.x, bb = blockIdx.x;
    const int s = tid & 7, grp = tid >> 3;

    h2 wh[8][8];
#pragma unroll
    for (int i = 0; i < 8; i++) {
        int g = grp * 8 + i;
#pragma unroll
        for (int kk = 0; kk < 8; kk++) {
            int k = 16 * s + 2 * kk;
            h2 p; p[0] = (f16)Whh[(size_t)g * HDIM + k]; p[1] = (f16)Whh[(size_t)g * HDIM + k + 1];
            wh[i][kk] = p;
        }
    }
    float c = 0.f;
    if (tid < HDIM) {
        float hv = 0.f;
        if (!init) { hv = hS[bb * HDIM + tid]; c = cS[bb * HDIM + tid]; }
        hbuf[tid] = (f16)hv;
    }
    // ---- gx prefetch ring (8 deep; lane-coalesced 128B/wave loads) ----
    const ushort* gp = (const ushort*)gx + (size_t)bb * 512 + tid;
    ushort gxr[8];
#pragma unroll
    for (int j = 0; j < 8; j++) gxr[j] = gp[(size_t)j * (B * 512)];
    __syncthreads();

    for (int w8 = 0; w8 < CH / 8; w8++) {
#pragma unroll
        for (int j = 0; j < 8; j++) {
            const int t = w8 * 8 + j;
            union { ushort u; f16 h; } GU; GU.u = gxr[j];
            float gxv = (float)GU.h;
            int tn = t + 8; if (tn > CH - 1) tn = CH - 1;
            gxr[j] = gp[(size_t)tn * (B * 512)];

            // ---- h-dot: slice read (2x b128 broadcast) + 64 dot2 ----
            union { uint4 u[2]; h2 h[8]; } S;
            S.u[0] = *(const uint4*)(&hbuf[16 * s]);
            S.u[1] = *(const uint4*)(&hbuf[16 * s + 8]);
            float acc[8];
#pragma unroll
            for (int i = 0; i < 8; i++) acc[i] = 0.f;
#pragma unroll
            for (int kk = 0; kk < 8; kk++) {
#pragma unroll
                for (int i = 0; i < 8; i++) acc[i] = dot2(wh[i][kk], S.h[kk], acc[i]);
            }
            // ---- split-tree reduce: lane s ends with gate grp*8+s = tid ----
            const int h4 = s & 4, h2b = s & 2, h1 = s & 1;
            float q0 = (h4 ? acc[4] : acc[0]) + __shfl_xor(h4 ? acc[0] : acc[4], 4);
            float q1 = (h4 ? acc[5] : acc[1]) + __shfl_xor(h4 ? acc[1] : acc[5], 4);
            float q2 = (h4 ? acc[6] : acc[2]) + __shfl_xor(h4 ? acc[2] : acc[6], 4);
            float q3 = (h4 ? acc[7] : acc[3]) + __shfl_xor(h4 ? acc[3] : acc[7], 4);
            float r0 = (h2b ? q2 : q0) + __shfl_xor(h2b ? q0 : q2, 2);
            float r1 = (h2b ? q3 : q1) + __shfl_xor(h2b ? q1 : q3, 2);
            float v  = (h1 ? r1 : r0) + __shfl_xor(h1 ? r0 : r1, 1);
            v += gxv;   // x-half + both biases (from pre-GEMM)

            // ---- activation (wave-uniform gate type: tid>>7; 2=g -> tanh) ----
            const int gt = tid >> 7;
            float act = (gt == 2) ? tanh_(v) : sigm(v);
            gbuf[tid] = act;
            bar();

            // ---- c/h update (threads 0..127) ----
            if (tid < HDIM) {
                float gi = gbuf[tid], gf = gbuf[128 + tid], gg = gbuf[256 + tid], go = gbuf[384 + tid];
                c = gf * c + gi * gg;
                float hh = go * tanh_(c);
                hbuf[tid] = (f16)hh;
                y[((size_t)(t0 + t) * B + bb) * HDIM + tid] = (f16)hh;
            }
            bar();
        }
    }
    if (tid < HDIM) {
        hS[bb * HDIM + tid] = (float)hbuf[tid];
        cS[bb * HDIM + tid] = c;
    }
}

// ---------------- fc2: y[T,B,128] f16 -> out[B,T,32] f32 ----------------
__global__ __launch_bounds__(256) void fc2_kernel(
    const f16* __restrict__ yin,
    const unsigned int* __restrict__ w1,  // [64][64] half2-packed Wf1
    const float* __restrict__ bf1,
    const float* __restrict__ Wf2,        // [32][64] f32
    const float* __restrict__ bf2,
    float* __restrict__ out) {
    int r = blockIdx.x * 256 + threadIdx.x;   // r = t*B + b
    union { uint4 u4[16]; h2 h[64]; } Y;
    {
        const uint4* yr4 = (const uint4*)(yin + (size_t)r * 128);
#pragma unroll
        for (int i = 0; i < 16; i++) Y.u4[i] = yr4[i];
    }
    float acc2[32];
#pragma unroll
    for (int i = 0; i < 32; i++) acc2[i] = 0.f;

    for (int cO = 0; cO < 64; cO++) {   // rolled: z1[cO] consumed immediately
        float a0 = bf1[cO], a1 = 0.f, a2 = 0.f, a3 = 0.f;
#pragma unroll
        for (int kk = 0; kk < 64; kk += 4) {
            union { unsigned int u; h2 h; } W0, W1x, W2x, W3;
            W0.u = w1[cO * 64 + kk];      a0 = dot2(W0.h,  Y.h[kk],     a0);
            W1x.u = w1[cO * 64 + kk + 1]; a1 = dot2(W1x.h, Y.h[kk + 1], a1);
            W2x.u = w1[cO * 64 + kk + 2]; a2 = dot2(W2x.h, Y.h[kk + 2], a2);
            W3.u = w1[cO * 64 + kk + 3];  a3 = dot2(W3.h,  Y.h[kk + 3], a3);
        }
        float a = fmaxf((a0 + a1) + (a2 + a3), 0.f);
#pragma unroll
        for (int c2 = 0; c2 < 32; c2++) acc2[c2] = fmaf(a, Wf2[c2 * 64 + cO], acc2[c2]);
    }
    float* orow = out + ((size_t)(r & 255) * T + (r >> 8)) * 32;
#pragma unroll
    for (int c2 = 0; c2 < 32; c2++) orow[c2] = fmaxf(acc2[c2] + bf2[c2], 0.f);
}

// ---------------- launch ----------------
extern "C" void kernel_launch(void* const* d_in, const int* in_sizes, int n_in,
                              void* d_out, int out_size, void* d_ws, size_t ws_size,
                              hipStream_t stream) {
    const float* scent = (const float*)d_in[0];
    const float* W1 = (const float*)d_in[1];
    const float* b1 = (const float*)d_in[2];
    const float* W2 = (const float*)d_in[3];
    const float* b2 = (const float*)d_in[4];
    const float* Wih[3] = {(const float*)d_in[5], (const float*)d_in[9], (const float*)d_in[13]};
    const float* Whh[3] = {(const float*)d_in[6], (const float*)d_in[10], (const float*)d_in[14]};
    const float* bihp[3] = {(const float*)d_in[7], (const float*)d_in[11], (const float*)d_in[15]};
    const float* bhhp[3] = {(const float*)d_in[8], (const float*)d_in[12], (const float*)d_in[16]};
    const float* Wf1 = (const float*)d_in[17];
    const float* bf1 = (const float*)d_in[18];
    const float* Wf2 = (const float*)d_in[19];
    const float* bf2 = (const float*)d_in[20];

    const size_t o_x1 = 0;                       // 32 MB: x1 [T,B,32] f16
    const size_t o_y  = 33554432;                // 128 MB: yb [T,B,128] f16
    const size_t o_gx = o_y + 134217728;         // 64 MB: gx [CH,B,512] f16
    const size_t o_w1 = o_gx + 67108864;         // 16 KB: packed Wf1
    const size_t need = o_w1 + 16384;
    if (ws_size < need) return;

    char* ws = (char*)d_ws;
    f16* x1 = (f16*)(ws + o_x1);
    f16* yb = (f16*)(ws + o_y);
    f16* gxb = (f16*)(ws + o_gx);
    unsigned int* w1p = (unsigned int*)(ws + o_w1);

    float* out = (float*)d_out;
    float* hO = out + (size_t)B * T * 32;
    float* cO = hO + 3 * B * HDIM;

    pack_kernel<<<16, 256, 0, stream>>>(Wf1, w1p);
    fc1_kernel<<<(B * T) / 256, 256, 0, stream>>>(scent, W1, b1, W2, b2, x1);

    dim3 ggrid(CH * B / 64, 4);
    for (int l = 0; l < 3; l++) {
        float* hS = hO + (size_t)l * B * HDIM;
        float* cS = cO + (size_t)l * B * HDIM;
        for (int ch = 0; ch < NCHUNK; ch++) {
            int t0 = ch * CH;
            if (l == 0)
                gx_gemm<32, 24, 40><<<ggrid, 256, 0, stream>>>(x1, Wih[0], bihp[0], bhhp[0], gxb, t0);
            else
                gx_gemm<128, 128, 144><<<ggrid, 256, 0, stream>>>(yb, Wih[l], bihp[l], bhhp[l], gxb, t0);
            lstm_rec<<<B, 512, 0, stream>>>(gxb, Whh[l], yb, hS, cS, t0, ch == 0 ? 1 : 0);
        }
    }
    fc2_kernel<<<(B * T) / 256, 256, 0, stream>>>(yb, w1p, bf1, Wf2, bf2, out);
}

// Round 6
// 5663.729 us; speedup vs baseline: 1.1506x; 1.1506x over previous
//
#include <hip/hip_runtime.h>

#define B 256
#define T 2048
#define HDIM 128
#define CH 256
#define NCHUNK (T / CH)

typedef _Float16 f16;
typedef _Float16 h2 __attribute__((ext_vector_type(2)));
typedef _Float16 f16x8 __attribute__((ext_vector_type(8)));
typedef float f32x4 __attribute__((ext_vector_type(4)));

__device__ __forceinline__ float dot2(h2 a, h2 b, float c) {
#if __has_builtin(__builtin_amdgcn_fdot2)
    return __builtin_amdgcn_fdot2(a, b, c, false);
#else
    return c + (float)a[0] * (float)b[0] + (float)a[1] * (float)b[1];
#endif
}

__device__ __forceinline__ float rcp_(float x) {
#if __has_builtin(__builtin_amdgcn_rcpf)
    return __builtin_amdgcn_rcpf(x);
#else
    return 1.0f / x;
#endif
}
// sigm via v_rcp (approx, ~1e-6 rel err -- fine vs 1e-2 threshold)
__device__ __forceinline__ float sigm(float x) { return rcp_(1.0f + __expf(-x)); }
// tanh(x) = 2/(1+e^{-2|x|}) - 1, sign restored
__device__ __forceinline__ float tanh_(float x) {
    float e = __expf(-2.0f * fabsf(x));
    float t = fmaf(2.0f, rcp_(1.0f + e), -1.0f);
    return copysignf(t, x);
}

__device__ __forceinline__ void bar() {
    // LDS-only barrier: order ds ops but do NOT drain vmcnt (keeps prefetch
    // loads and y-stores in flight across the barrier).
    asm volatile("s_waitcnt lgkmcnt(0)" ::: "memory");
    __builtin_amdgcn_s_barrier();
}

// ---------------- fc1: scent[B,T,3] -> x1[T,B,32] f16 (24 real + 8 zero pad) ---------
__global__ __launch_bounds__(256) void fc1_kernel(
    const float* __restrict__ scent,
    const float* __restrict__ W1, const float* __restrict__ b1,
    const float* __restrict__ W2, const float* __restrict__ b2,
    f16* __restrict__ x1) {
    int r = blockIdx.x * 256 + threadIdx.x;   // r = b*T + t
    int b = r >> 11, t = r & 2047;
    float s0 = scent[r * 3], s1 = scent[r * 3 + 1], s2 = scent[r * 3 + 2];
    float a[12];
#pragma unroll
    for (int i = 0; i < 12; i++) {
        float v = W1[i * 3] * s0 + W1[i * 3 + 1] * s1 + W1[i * 3 + 2] * s2 + b1[i];
        a[i] = fmaxf(v, 0.f);
    }
    union { f16 o[32]; uint4 u[4]; } U;
#pragma unroll
    for (int j = 0; j < 24; j++) {
        float v = b2[j];
#pragma unroll
        for (int i = 0; i < 12; i++) v = fmaf(W2[j * 12 + i], a[i], v);
        U.o[j] = (f16)fmaxf(v, 0.f);
    }
#pragma unroll
    for (int j = 24; j < 32; j++) U.o[j] = (f16)0.f;
    uint4* d4 = (uint4*)(x1 + ((size_t)t * B + b) * 32);
#pragma unroll
    for (int i = 0; i < 4; i++) d4[i] = U.u[i];
}

// ---------------- pack Wf1 f32 -> half2 ----------------
__global__ __launch_bounds__(256) void pack_kernel(const float* __restrict__ w,
                                                   unsigned int* __restrict__ o) {
    int i = blockIdx.x * 256 + threadIdx.x;
    if (i < 4096) {
        union { h2 h; unsigned int u; } U;
        U.h[0] = (f16)w[2 * i];
        U.h[1] = (f16)w[2 * i + 1];
        o[i] = U.u;
    }
}

// ---------------- gx pre-GEMM: gx[r,g] = x[r,:]@Wih^T + bih + bhh (one chunk) --------
// Block: 64 rows x 128 gates; 4 waves, wave = 32 rows x 64 gates
// = 2 row-tiles x 4 gate-tiles (16x16) x KF kfrags of mfma_f32_16x16x32_f16.
template <int KIN, int KREAL, int SP>
__global__ __launch_bounds__(256) void gx_gemm(
    const f16* __restrict__ x,     // [T][B][KIN]
    const float* __restrict__ Wih, // [512][KREAL]
    const float* __restrict__ bih, const float* __restrict__ bhh,
    f16* __restrict__ gx,          // [CH*B][512]
    int t0) {
    constexpr int KF = KIN / 32;
    __shared__ __align__(16) f16 Alds[64 * SP];   // SP: padded row stride (bank spread)
    const int tid = threadIdx.x;
    const int mb = blockIdx.x, nb = blockIdx.y;
    const int l = tid & 63, wv = tid >> 6;
    const int lc = l & 15, lg = l >> 4;

    // ---- stage A slab: 64 consecutive (t,b) rows ----
    const f16* xrow = x + ((size_t)t0 * B + (size_t)mb * 64) * KIN;
    if (KIN == 128) {
#pragma unroll
        for (int it = 0; it < 4; it++) {
            int row = it * 16 + (tid >> 4), cc = tid & 15;
            uint4 v = *(const uint4*)(xrow + (size_t)row * KIN + cc * 8);
            *(uint4*)(&Alds[row * SP + cc * 8]) = v;
        }
    } else {
        int row = tid >> 2, cc = tid & 3;
        uint4 v = *(const uint4*)(xrow + (size_t)row * KIN + cc * 8);
        *(uint4*)(&Alds[row * SP + cc * 8]) = v;
    }

    // ---- B fragments (Wih f32 -> f16) + bias, registers ----
    const int gbase = nb * 128 + (wv & 1) * 64;
    const int rbase = (wv >> 1) * 32;
    f16x8 bf[4][KF];
    float bias4[4];
#pragma unroll
    for (int gt = 0; gt < 4; gt++) {
        int g = gbase + gt * 16 + lc;
        bias4[gt] = bih[g] + bhh[g];
#pragma unroll
        for (int kf = 0; kf < KF; kf++) {
            f16x8 v;
#pragma unroll
            for (int j = 0; j < 8; j++) {
                int k = kf * 32 + lg * 8 + j;
                v[j] = (k < KREAL) ? (f16)Wih[(size_t)g * KREAL + k] : (f16)0.f;
            }
            bf[gt][kf] = v;
        }
    }
    __syncthreads();

    f32x4 acc[2][4] = {};
#pragma unroll
    for (int kf = 0; kf < KF; kf++) {
#pragma unroll
        for (int rt = 0; rt < 2; rt++) {
            f16x8 af = *(const f16x8*)(&Alds[(rbase + rt * 16 + lc) * SP + kf * 32 + lg * 8]);
#pragma unroll
            for (int gt = 0; gt < 4; gt++)
                acc[rt][gt] = __builtin_amdgcn_mfma_f32_16x16x32_f16(af, bf[gt][kf], acc[rt][gt], 0, 0, 0);
        }
    }
    // ---- epilogue: C row = lg*4+q, col = lc (m89-verified layout) ----
#pragma unroll
    for (int rt = 0; rt < 2; rt++)
#pragma unroll
        for (int gt = 0; gt < 4; gt++)
#pragma unroll
            for (int q = 0; q < 4; q++) {
                int rr = mb * 64 + rbase + rt * 16 + lg * 4 + q;
                int gg = gbase + gt * 16 + lc;
                gx[(size_t)rr * 512 + gg] = (f16)(acc[rt][gt][q] + bias4[gt]);
            }
}

// ---------------- recurrence: one block (512 thr) per batch row, one chunk ----------
// Quad decomposition: thread (j = tid>>2, q = tid&3) computes partial dots for
// ALL 4 gates of h-unit j over k-slice [32q, 32q+32). 2-level shfl_xor butterfly
// (quad_perm, bit-identical across lanes) leaves all 4 full gate sums on every
// lane -> cell update in-register on all lanes (redundant), NO gbuf round-trip,
// ONE barrier per step. hbuf double-buffered so one barrier suffices.
__global__ __attribute__((amdgpu_flat_work_group_size(512, 512), amdgpu_waves_per_eu(2, 2)))
void lstm_rec(
    const f16* __restrict__ gx,    // [CH*B][512]
    const float* __restrict__ Whh, // [512][128]
    f16* __restrict__ y,           // [T][B][128]
    float* __restrict__ hS, float* __restrict__ cS,  // [B][128] state (= hT/cT out)
    int t0, int init) {
    __shared__ __align__(16) f16 hbuf[2][HDIM];
    const int tid = threadIdx.x, bb = blockIdx.x;
    const int j = tid >> 2, q = tid & 3;

    // ---- weights: gates {j, 128+j, 256+j, 384+j}, k in [32q, 32q+32) ----
    h2 wh[4][16];
#pragma unroll
    for (int gi = 0; gi < 4; gi++) {
        const float* wr = Whh + (size_t)(gi * 128 + j) * HDIM + 32 * q;
#pragma unroll
        for (int kk = 0; kk < 16; kk++) {
            h2 p; p[0] = (f16)wr[2 * kk]; p[1] = (f16)wr[2 * kk + 1];
            wh[gi][kk] = p;
        }
    }
    float c = 0.f;
    {
        float hv = 0.f;
        if (!init) { hv = hS[bb * HDIM + j]; c = cS[bb * HDIM + j]; }
        if (q == 0) hbuf[0][j] = (f16)hv;
    }
    // ---- gx prefetch ring (8 deep): thread reads gate q*128+j ----
    const ushort* gp = (const ushort*)gx + (size_t)bb * 512 + q * 128 + j;
    ushort gxr[8];
#pragma unroll
    for (int jj = 0; jj < 8; jj++) gxr[jj] = gp[(size_t)jj * (B * 512)];
    __syncthreads();

    float hh = 0.f;
    for (int w8 = 0; w8 < CH / 8; w8++) {
#pragma unroll
        for (int jj = 0; jj < 8; jj++) {
            const int t = w8 * 8 + jj;
            const int p = t & 1;
            union { ushort u; f16 h; } GU; GU.u = gxr[jj];
            float gxv = (float)GU.h;
            int tn = t + 8; if (tn > CH - 1) tn = CH - 1;
            gxr[jj] = gp[(size_t)tn * (B * 512)];

            // ---- slice read: 32 f16 of h_{t-1} (4x b128; 2-way bank alias = free) ----
            union { uint4 u[4]; h2 h[16]; } S;
            {
                const uint4* kp = (const uint4*)(&hbuf[p][32 * q]);
                S.u[0] = kp[0]; S.u[1] = kp[1]; S.u[2] = kp[2]; S.u[3] = kp[3];
            }
            // ---- partial dots for 4 gates; gx folded into acc[q]'s gate ----
            float acc[4];
#pragma unroll
            for (int gi = 0; gi < 4; gi++) acc[gi] = (q == gi) ? gxv : 0.f;
#pragma unroll
            for (int kk = 0; kk < 16; kk++) {
#pragma unroll
                for (int gi = 0; gi < 4; gi++) acc[gi] = dot2(wh[gi][kk], S.h[kk], acc[gi]);
            }
            // ---- quad butterfly: every lane gets all 4 full gate sums ----
#pragma unroll
            for (int gi = 0; gi < 4; gi++) {
                acc[gi] += __shfl_xor(acc[gi], 1);
                acc[gi] += __shfl_xor(acc[gi], 2);
            }
            // ---- cell update (redundant on all 4 lanes; bit-identical) ----
            float gi_ = sigm(acc[0]), gf_ = sigm(acc[1]);
            float gg_ = tanh_(acc[2]), go_ = sigm(acc[3]);
            c = gf_ * c + gi_ * gg_;
            hh = go_ * tanh_(c);
            if (q == 0) {
                hbuf[p ^ 1][j] = (f16)hh;
                y[((size_t)(t0 + t) * B + bb) * HDIM + j] = (f16)hh;
            }
            bar();
        }
    }
    if (q == 0) {
        hS[bb * HDIM + j] = hh;
        cS[bb * HDIM + j] = c;
    }
}

// ---------------- fc2: y[T,B,128] f16 -> out[B,T,32] f32 ----------------
__global__ __launch_bounds__(256) void fc2_kernel(
    const f16* __restrict__ yin,
    const unsigned int* __restrict__ w1,  // [64][64] half2-packed Wf1
    const float* __restrict__ bf1,
    const float* __restrict__ Wf2,        // [32][64] f32
    const float* __restrict__ bf2,
    float* __restrict__ out) {
    int r = blockIdx.x * 256 + threadIdx.x;   // r = t*B + b
    union { uint4 u4[16]; h2 h[64]; } Y;
    {
        const uint4* yr4 = (const uint4*)(yin + (size_t)r * 128);
#pragma unroll
        for (int i = 0; i < 16; i++) Y.u4[i] = yr4[i];
    }
    float acc2[32];
#pragma unroll
    for (int i = 0; i < 32; i++) acc2[i] = 0.f;

    for (int cO = 0; cO < 64; cO++) {   // rolled: z1[cO] consumed immediately
        float a0 = bf1[cO], a1 = 0.f, a2 = 0.f, a3 = 0.f;
#pragma unroll
        for (int kk = 0; kk < 64; kk += 4) {
            union { unsigned int u; h2 h; } W0, W1x, W2x, W3;
            W0.u = w1[cO * 64 + kk];      a0 = dot2(W0.h,  Y.h[kk],     a0);
            W1x.u = w1[cO * 64 + kk + 1]; a1 = dot2(W1x.h, Y.h[kk + 1], a1);
            W2x.u = w1[cO * 64 + kk + 2]; a2 = dot2(W2x.h, Y.h[kk + 2], a2);
            W3.u = w1[cO * 64 + kk + 3];  a3 = dot2(W3.h,  Y.h[kk + 3], a3);
        }
        float a = fmaxf((a0 + a1) + (a2 + a3), 0.f);
#pragma unroll
        for (int c2 = 0; c2 < 32; c2++) acc2[c2] = fmaf(a, Wf2[c2 * 64 + cO], acc2[c2]);
    }
    float* orow = out + ((size_t)(r & 255) * T + (r >> 8)) * 32;
#pragma unroll
    for (int c2 = 0; c2 < 32; c2++) orow[c2] = fmaxf(acc2[c2] + bf2[c2], 0.f);
}

// ---------------- launch ----------------
extern "C" void kernel_launch(void* const* d_in, const int* in_sizes, int n_in,
                              void* d_out, int out_size, void* d_ws, size_t ws_size,
                              hipStream_t stream) {
    const float* scent = (const float*)d_in[0];
    const float* W1 = (const float*)d_in[1];
    const float* b1 = (const float*)d_in[2];
    const float* W2 = (const float*)d_in[3];
    const float* b2 = (const float*)d_in[4];
    const float* Wih[3] = {(const float*)d_in[5], (const float*)d_in[9], (const float*)d_in[13]};
    const float* Whh[3] = {(const float*)d_in[6], (const float*)d_in[10], (const float*)d_in[14]};
    const float* bihp[3] = {(const float*)d_in[7], (const float*)d_in[11], (const float*)d_in[15]};
    const float* bhhp[3] = {(const float*)d_in[8], (const float*)d_in[12], (const float*)d_in[16]};
    const float* Wf1 = (const float*)d_in[17];
    const float* bf1 = (const float*)d_in[18];
    const float* Wf2 = (const float*)d_in[19];
    const float* bf2 = (const float*)d_in[20];

    const size_t o_x1 = 0;                       // 32 MB: x1 [T,B,32] f16
    const size_t o_y  = 33554432;                // 128 MB: yb [T,B,128] f16
    const size_t o_gx = o_y + 134217728;         // 64 MB: gx [CH,B,512] f16
    const size_t o_w1 = o_gx + 67108864;         // 16 KB: packed Wf1
    const size_t need = o_w1 + 16384;
    if (ws_size < need) return;

    char* ws = (char*)d_ws;
    f16* x1 = (f16*)(ws + o_x1);
    f16* yb = (f16*)(ws + o_y);
    f16* gxb = (f16*)(ws + o_gx);
    unsigned int* w1p = (unsigned int*)(ws + o_w1);

    float* out = (float*)d_out;
    float* hO = out + (size_t)B * T * 32;
    float* cO = hO + 3 * B * HDIM;

    pack_kernel<<<16, 256, 0, stream>>>(Wf1, w1p);
    fc1_kernel<<<(B * T) / 256, 256, 0, stream>>>(scent, W1, b1, W2, b2, x1);

    dim3 ggrid(CH * B / 64, 4);
    for (int l = 0; l < 3; l++) {
        float* hS = hO + (size_t)l * B * HDIM;
        float* cS = cO + (size_t)l * B * HDIM;
        for (int ch = 0; ch < NCHUNK; ch++) {
            int t0 = ch * CH;
            if (l == 0)
                gx_gemm<32, 24, 40><<<ggrid, 256, 0, stream>>>(x1, Wih[0], bihp[0], bhhp[0], gxb, t0);
            else
                gx_gemm<128, 128, 144><<<ggrid, 256, 0, stream>>>(yb, Wih[l], bihp[l], bhhp[l], gxb, t0);
            lstm_rec<<<B, 512, 0, stream>>>(gxb, Whh[l], yb, hS, cS, t0, ch == 0 ? 1 : 0);
        }
    }
    fc2_kernel<<<(B * T) / 256, 256, 0, stream>>>(yb, w1p, bf1, Wf2, bf2, out);
}

// Round 7
// 5214.428 us; speedup vs baseline: 1.2497x; 1.0862x over previous
//
#include <hip/hip_runtime.h>

#define B 256
#define T 2048
#define HDIM 128
#define CH 256
#define NCHUNK (T / CH)

typedef _Float16 f16;
typedef _Float16 h2 __attribute__((ext_vector_type(2)));
typedef _Float16 f16x8 __attribute__((ext_vector_type(8)));
typedef float f32x4 __attribute__((ext_vector_type(4)));

__device__ __forceinline__ float dot2(h2 a, h2 b, float c) {
#if __has_builtin(__builtin_amdgcn_fdot2)
    return __builtin_amdgcn_fdot2(a, b, c, false);
#else
    return c + (float)a[0] * (float)b[0] + (float)a[1] * (float)b[1];
#endif
}

__device__ __forceinline__ float rcp_(float x) {
#if __has_builtin(__builtin_amdgcn_rcpf)
    return __builtin_amdgcn_rcpf(x);
#else
    return 1.0f / x;
#endif
}
// sigm via v_rcp (approx, ~1e-6 rel err -- fine vs 1e-2 threshold)
__device__ __forceinline__ float sigm(float x) { return rcp_(1.0f + __expf(-x)); }
// tanh(x) = 2/(1+e^{-2|x|}) - 1, sign restored
__device__ __forceinline__ float tanh_(float x) {
    float e = __expf(-2.0f * fabsf(x));
    float t = fmaf(2.0f, rcp_(1.0f + e), -1.0f);
    return copysignf(t, x);
}

__device__ __forceinline__ void bar() {
    // LDS-only barrier: order ds ops but do NOT drain vmcnt (keeps prefetch
    // loads and y-stores in flight across the barrier).
    asm volatile("s_waitcnt lgkmcnt(0)" ::: "memory");
    __builtin_amdgcn_s_barrier();
}

// ---------------- fc1: scent[B,T,3] -> x1[T,B,32] f16 (24 real + 8 zero pad) ---------
__global__ __launch_bounds__(256) void fc1_kernel(
    const float* __restrict__ scent,
    const float* __restrict__ W1, const float* __restrict__ b1,
    const float* __restrict__ W2, const float* __restrict__ b2,
    f16* __restrict__ x1) {
    int r = blockIdx.x * 256 + threadIdx.x;   // r = b*T + t
    int b = r >> 11, t = r & 2047;
    float s0 = scent[r * 3], s1 = scent[r * 3 + 1], s2 = scent[r * 3 + 2];
    float a[12];
#pragma unroll
    for (int i = 0; i < 12; i++) {
        float v = W1[i * 3] * s0 + W1[i * 3 + 1] * s1 + W1[i * 3 + 2] * s2 + b1[i];
        a[i] = fmaxf(v, 0.f);
    }
    union { f16 o[32]; uint4 u[4]; } U;
#pragma unroll
    for (int j = 0; j < 24; j++) {
        float v = b2[j];
#pragma unroll
        for (int i = 0; i < 12; i++) v = fmaf(W2[j * 12 + i], a[i], v);
        U.o[j] = (f16)fmaxf(v, 0.f);
    }
#pragma unroll
    for (int j = 24; j < 32; j++) U.o[j] = (f16)0.f;
    uint4* d4 = (uint4*)(x1 + ((size_t)t * B + b) * 32);
#pragma unroll
    for (int i = 0; i < 4; i++) d4[i] = U.u[i];
}

// ---------------- pack Wf1 f32 -> half2 ----------------
__global__ __launch_bounds__(256) void pack_kernel(const float* __restrict__ w,
                                                   unsigned int* __restrict__ o) {
    int i = blockIdx.x * 256 + threadIdx.x;
    if (i < 4096) {
        union { h2 h; unsigned int u; } U;
        U.h[0] = (f16)w[2 * i];
        U.h[1] = (f16)w[2 * i + 1];
        o[i] = U.u;
    }
}

// ---------------- gx pre-GEMM: gx[r,g] = x[r,:]@Wih^T + bih + bhh (one chunk) --------
// Block: 64 rows x 128 gates; 4 waves, wave = 32 rows x 64 gates
// = 2 row-tiles x 4 gate-tiles (16x16) x KF kfrags of mfma_f32_16x16x32_f16.
template <int KIN, int KREAL, int SP>
__global__ __launch_bounds__(256) void gx_gemm(
    const f16* __restrict__ x,     // [T][B][KIN]
    const float* __restrict__ Wih, // [512][KREAL]
    const float* __restrict__ bih, const float* __restrict__ bhh,
    f16* __restrict__ gx,          // [CH*B][512]
    int t0) {
    constexpr int KF = KIN / 32;
    __shared__ __align__(16) f16 Alds[64 * SP];   // SP: padded row stride (bank spread)
    const int tid = threadIdx.x;
    const int mb = blockIdx.x, nb = blockIdx.y;
    const int l = tid & 63, wv = tid >> 6;
    const int lc = l & 15, lg = l >> 4;

    // ---- stage A slab: 64 consecutive (t,b) rows ----
    const f16* xrow = x + ((size_t)t0 * B + (size_t)mb * 64) * KIN;
    if (KIN == 128) {
#pragma unroll
        for (int it = 0; it < 4; it++) {
            int row = it * 16 + (tid >> 4), cc = tid & 15;
            uint4 v = *(const uint4*)(xrow + (size_t)row * KIN + cc * 8);
            *(uint4*)(&Alds[row * SP + cc * 8]) = v;
        }
    } else {
        int row = tid >> 2, cc = tid & 3;
        uint4 v = *(const uint4*)(xrow + (size_t)row * KIN + cc * 8);
        *(uint4*)(&Alds[row * SP + cc * 8]) = v;
    }

    // ---- B fragments (Wih f32 -> f16) + bias, registers ----
    const int gbase = nb * 128 + (wv & 1) * 64;
    const int rbase = (wv >> 1) * 32;
    f16x8 bf[4][KF];
    float bias4[4];
#pragma unroll
    for (int gt = 0; gt < 4; gt++) {
        int g = gbase + gt * 16 + lc;
        bias4[gt] = bih[g] + bhh[g];
#pragma unroll
        for (int kf = 0; kf < KF; kf++) {
            f16x8 v;
#pragma unroll
            for (int j = 0; j < 8; j++) {
                int k = kf * 32 + lg * 8 + j;
                v[j] = (k < KREAL) ? (f16)Wih[(size_t)g * KREAL + k] : (f16)0.f;
            }
            bf[gt][kf] = v;
        }
    }
    __syncthreads();

    f32x4 acc[2][4] = {};
#pragma unroll
    for (int kf = 0; kf < KF; kf++) {
#pragma unroll
        for (int rt = 0; rt < 2; rt++) {
            f16x8 af = *(const f16x8*)(&Alds[(rbase + rt * 16 + lc) * SP + kf * 32 + lg * 8]);
#pragma unroll
            for (int gt = 0; gt < 4; gt++)
                acc[rt][gt] = __builtin_amdgcn_mfma_f32_16x16x32_f16(af, bf[gt][kf], acc[rt][gt], 0, 0, 0);
        }
    }
    // ---- epilogue: C row = lg*4+q, col = lc (m89-verified layout) ----
#pragma unroll
    for (int rt = 0; rt < 2; rt++)
#pragma unroll
        for (int gt = 0; gt < 4; gt++)
#pragma unroll
            for (int q = 0; q < 4; q++) {
                int rr = mb * 64 + rbase + rt * 16 + lg * 4 + q;
                int gg = gbase + gt * 16 + lc;
                gx[(size_t)rr * 512 + gg] = (f16)(acc[rt][gt][q] + bias4[gt]);
            }
}

// ---------------- recurrence: one block (256 thr) per batch row, one chunk ----------
// thread = (j = tid>>1 : h-unit, q = tid&1 : 64-wide k-half). Each thread computes
// partial dots for ALL 4 gates of unit j over its k-half (4 chains x 32 dot2);
// ONE shfl_xor(1) level completes all 4 gate sums on both lanes -> cell update
// in-register (redundant x2), no gbuf, ONE barrier/step. gx folded into acc init
// (q=0 lanes carry i,f; q=1 lanes carry g,o). waves_per_eu(1,1) -> 512-VGPR cap:
// 128-dword weight array + 32-dword slice live entirely in arch VGPRs.
__global__ __attribute__((amdgpu_flat_work_group_size(256, 256), amdgpu_waves_per_eu(1, 1)))
void lstm_rec(
    const f16* __restrict__ gx,    // [CH*B][512]
    const float* __restrict__ Whh, // [512][128]
    f16* __restrict__ y,           // [T][B][128]
    float* __restrict__ hS, float* __restrict__ cS,  // [B][128] state (= hT/cT out)
    int t0, int init) {
    __shared__ __align__(16) f16 hbuf[2][HDIM];
    const int tid = threadIdx.x, bb = blockIdx.x;
    const int j = tid >> 1, q = tid & 1;

    // ---- weights: gates {j, 128+j, 256+j, 384+j}, k in [64q, 64q+64) ----
    h2 wh[4][32];
#pragma unroll
    for (int gi = 0; gi < 4; gi++) {
        const float* wr = Whh + (size_t)(gi * 128 + j) * HDIM + 64 * q;
#pragma unroll
        for (int kk = 0; kk < 32; kk++) {
            h2 p; p[0] = (f16)wr[2 * kk]; p[1] = (f16)wr[2 * kk + 1];
            wh[gi][kk] = p;
        }
    }
    float c = 0.f;
    {
        float hv = 0.f;
        if (!init) { hv = hS[bb * HDIM + j]; c = cS[bb * HDIM + j]; }
        if (q == 0) hbuf[0][j] = (f16)hv;
    }
    // ---- gx prefetch ring (4 deep): q=0 lanes carry gates {0,1}=i,f; q=1 -> {2,3}=g,o
    const ushort* gp0 = (const ushort*)gx + (size_t)bb * 512 + (2 * q) * 128 + j;
    const ushort* gp1 = gp0 + 128;
    ushort ga[4], gb[4];
#pragma unroll
    for (int jj = 0; jj < 4; jj++) {
        ga[jj] = gp0[(size_t)jj * (B * 512)];
        gb[jj] = gp1[(size_t)jj * (B * 512)];
    }
    __syncthreads();

    float hh = 0.f;
    for (int w4 = 0; w4 < CH / 4; w4++) {
#pragma unroll
        for (int jj = 0; jj < 4; jj++) {
            const int t = w4 * 4 + jj;
            const int p = t & 1;
            union { ushort u; f16 h; } GA, GB;
            GA.u = ga[jj]; GB.u = gb[jj];
            float gxa = (float)GA.h, gxb = (float)GB.h;
            int tn = t + 4; if (tn > CH - 1) tn = CH - 1;
            ga[jj] = gp0[(size_t)tn * (B * 512)];
            gb[jj] = gp1[(size_t)tn * (B * 512)];

            // ---- slice read: 64 f16 of h_{t-1} (8x b128; 2 addrs/instr = free) ----
            union { uint4 u[8]; h2 h[32]; } S;
            {
                const uint4* kp = (const uint4*)(&hbuf[p][64 * q]);
#pragma unroll
                for (int i = 0; i < 8; i++) S.u[i] = kp[i];
            }
            // ---- partial dots for 4 gates; gx folded into acc init ----
            float acc[4];
            acc[0] = (q == 0) ? gxa : 0.f;
            acc[1] = (q == 0) ? gxb : 0.f;
            acc[2] = (q == 1) ? gxa : 0.f;
            acc[3] = (q == 1) ? gxb : 0.f;
#pragma unroll
            for (int kk = 0; kk < 32; kk++) {
#pragma unroll
                for (int gi = 0; gi < 4; gi++) acc[gi] = dot2(wh[gi][kk], S.h[kk], acc[gi]);
            }
            // ---- one butterfly level: both lanes get all 4 full gate sums ----
#pragma unroll
            for (int gi = 0; gi < 4; gi++) acc[gi] += __shfl_xor(acc[gi], 1);

            // ---- cell update (redundant on both lanes; bit-identical) ----
            float gi_ = sigm(acc[0]), gf_ = sigm(acc[1]);
            float gg_ = tanh_(acc[2]), go_ = sigm(acc[3]);
            c = gf_ * c + gi_ * gg_;
            hh = go_ * tanh_(c);
            if (q == 0) {
                hbuf[p ^ 1][j] = (f16)hh;
                y[((size_t)(t0 + t) * B + bb) * HDIM + j] = (f16)hh;
            }
            bar();
        }
    }
    if (q == 0) {
        hS[bb * HDIM + j] = hh;
        cS[bb * HDIM + j] = c;
    }
}

// ---------------- fc2: y[T,B,128] f16 -> out[B,T,32] f32 ----------------
__global__ __launch_bounds__(256) void fc2_kernel(
    const f16* __restrict__ yin,
    const unsigned int* __restrict__ w1,  // [64][64] half2-packed Wf1
    const float* __restrict__ bf1,
    const float* __restrict__ Wf2,        // [32][64] f32
    const float* __restrict__ bf2,
    float* __restrict__ out) {
    int r = blockIdx.x * 256 + threadIdx.x;   // r = t*B + b
    union { uint4 u4[16]; h2 h[64]; } Y;
    {
        const uint4* yr4 = (const uint4*)(yin + (size_t)r * 128);
#pragma unroll
        for (int i = 0; i < 16; i++) Y.u4[i] = yr4[i];
    }
    float acc2[32];
#pragma unroll
    for (int i = 0; i < 32; i++) acc2[i] = 0.f;

    for (int cO = 0; cO < 64; cO++) {   // rolled: z1[cO] consumed immediately
        float a0 = bf1[cO], a1 = 0.f, a2 = 0.f, a3 = 0.f;
#pragma unroll
        for (int kk = 0; kk < 64; kk += 4) {
            union { unsigned int u; h2 h; } W0, W1x, W2x, W3;
            W0.u = w1[cO * 64 + kk];      a0 = dot2(W0.h,  Y.h[kk],     a0);
            W1x.u = w1[cO * 64 + kk + 1]; a1 = dot2(W1x.h, Y.h[kk + 1], a1);
            W2x.u = w1[cO * 64 + kk + 2]; a2 = dot2(W2x.h, Y.h[kk + 2], a2);
            W3.u = w1[cO * 64 + kk + 3];  a3 = dot2(W3.h,  Y.h[kk + 3], a3);
        }
        float a = fmaxf((a0 + a1) + (a2 + a3), 0.f);
#pragma unroll
        for (int c2 = 0; c2 < 32; c2++) acc2[c2] = fmaf(a, Wf2[c2 * 64 + cO], acc2[c2]);
    }
    float* orow = out + ((size_t)(r & 255) * T + (r >> 8)) * 32;
#pragma unroll
    for (int c2 = 0; c2 < 32; c2++) orow[c2] = fmaxf(acc2[c2] + bf2[c2], 0.f);
}

// ---------------- launch ----------------
extern "C" void kernel_launch(void* const* d_in, const int* in_sizes, int n_in,
                              void* d_out, int out_size, void* d_ws, size_t ws_size,
                              hipStream_t stream) {
    const float* scent = (const float*)d_in[0];
    const float* W1 = (const float*)d_in[1];
    const float* b1 = (const float*)d_in[2];
    const float* W2 = (const float*)d_in[3];
    const float* b2 = (const float*)d_in[4];
    const float* Wih[3] = {(const float*)d_in[5], (const float*)d_in[9], (const float*)d_in[13]};
    const float* Whh[3] = {(const float*)d_in[6], (const float*)d_in[10], (const float*)d_in[14]};
    const float* bihp[3] = {(const float*)d_in[7], (const float*)d_in[11], (const float*)d_in[15]};
    const float* bhhp[3] = {(const float*)d_in[8], (const float*)d_in[12], (const float*)d_in[16]};
    const float* Wf1 = (const float*)d_in[17];
    const float* bf1 = (const float*)d_in[18];
    const float* Wf2 = (const float*)d_in[19];
    const float* bf2 = (const float*)d_in[20];

    const size_t o_x1 = 0;                       // 32 MB: x1 [T,B,32] f16
    const size_t o_y  = 33554432;                // 128 MB: yb [T,B,128] f16
    const size_t o_gx = o_y + 134217728;         // 64 MB: gx [CH,B,512] f16
    const size_t o_w1 = o_gx + 67108864;         // 16 KB: packed Wf1
    const size_t need = o_w1 + 16384;
    if (ws_size < need) return;

    char* ws = (char*)d_ws;
    f16* x1 = (f16*)(ws + o_x1);
    f16* yb = (f16*)(ws + o_y);
    f16* gxb = (f16*)(ws + o_gx);
    unsigned int* w1p = (unsigned int*)(ws + o_w1);

    float* out = (float*)d_out;
    float* hO = out + (size_t)B * T * 32;
    float* cO = hO + 3 * B * HDIM;

    pack_kernel<<<16, 256, 0, stream>>>(Wf1, w1p);
    fc1_kernel<<<(B * T) / 256, 256, 0, stream>>>(scent, W1, b1, W2, b2, x1);

    dim3 ggrid(CH * B / 64, 4);
    for (int l = 0; l < 3; l++) {
        float* hS = hO + (size_t)l * B * HDIM;
        float* cS = cO + (size_t)l * B * HDIM;
        for (int ch = 0; ch < NCHUNK; ch++) {
            int t0 = ch * CH;
            if (l == 0)
                gx_gemm<32, 24, 40><<<ggrid, 256, 0, stream>>>(x1, Wih[0], bihp[0], bhhp[0], gxb, t0);
            else
                gx_gemm<128, 128, 144><<<ggrid, 256, 0, stream>>>(yb, Wih[l], bihp[l], bhhp[l], gxb, t0);
            lstm_rec<<<B, 256, 0, stream>>>(gxb, Whh[l], yb, hS, cS, t0, ch == 0 ? 1 : 0);
        }
    }
    fc2_kernel<<<(B * T) / 256, 256, 0, stream>>>(yb, w1p, bf1, Wf2, bf2, out);
}